// Round 13
// baseline (116.233 us; speedup 1.0000x reference)
//
#include <hip/hip_runtime.h>
#include <cfloat>
#include <cstdint>

#define NPTS 65536
#define DIM 256
#define NC 16
#define KSEL 2048
#define VMAX 4608
#define EPSV 1e-6f

// ws layout (bytes):
//     0 : float sums[16*256]   (16384)
// 16384 : int counts[16]       (64)
// 16512 : int offsets[16]      (64)
// 16576 : float csq[16]        (64)
// 16640 : float pos_stat[16]   (64)
// 16704 : float neg_stat[256]  (1024)
// 17728 : float centers[4096]  (16384)
// 34112 : int bhist[256*16]    (16384)
// 65536 : float Dmat[16*65536] (4 MB) -- also partials[256][4096] pre-k_dist
// 4259840 : int slots[65536]   (256 KB)

__global__ void __launch_bounds__(256) k_hist(const int* __restrict__ y,
                                              int* __restrict__ bhist) {
  __shared__ int h[NC];
  int t = threadIdx.x;
  if (t < NC) h[t] = 0;
  __syncthreads();
  int p = blockIdx.x * 256 + t;
  atomicAdd(&h[y[p * 3 + 2]], 1);
  __syncthreads();
  if (t < NC) bhist[blockIdx.x * NC + t] = h[t];
}

// Scan bhist per class across 256 chunks; also emits counts[] and offsets[].
__global__ void __launch_bounds__(256) k_scan(int* __restrict__ bhist,
                                              int* __restrict__ counts,
                                              int* __restrict__ offsets) {
  __shared__ int lh[256 * NC];
  __shared__ int segbase[16][NC];
  __shared__ int totl[NC], offl[NC];
  int t = threadIdx.x;
  for (int u = t; u < 256 * NC; u += 256) lh[u] = bhist[u];
  __syncthreads();
  int c = t & 15, g = t >> 4;
  int part = 0;
#pragma unroll
  for (int b = 0; b < 16; ++b) part += lh[(g * 16 + b) * NC + c];
  segbase[g][c] = part;
  __syncthreads();
  if (t < NC) {
    int tot = 0;
#pragma unroll
    for (int g2 = 0; g2 < 16; ++g2) tot += segbase[g2][t];
    totl[t] = tot;
    counts[t] = tot;
  }
  __syncthreads();
  if (t == 0) {
    int run = 0;
    for (int c2 = 0; c2 < NC; ++c2) { offl[c2] = run; offsets[c2] = run; run += totl[c2]; }
  }
  __syncthreads();
  if (t < NC) {
    int run = offl[t];
#pragma unroll
    for (int g2 = 0; g2 < 16; ++g2) { int tmp = segbase[g2][t]; segbase[g2][t] = run; run += tmp; }
  }
  __syncthreads();
  int run = segbase[g][c];
#pragma unroll
  for (int b = 0; b < 16; ++b) {
    int idx = (g * 16 + b) * NC + c;
    int tmp = lh[idx]; lh[idx] = run; run += tmp;
  }
  __syncthreads();
  for (int u = t; u < 256 * NC; u += 256) bhist[u] = lh[u];
}

// slot[p] = scanned chunk base + stable in-chunk rank.
__global__ void __launch_bounds__(256) k_slot(const int* __restrict__ y,
                                              const int* __restrict__ bbase,
                                              int* __restrict__ slots) {
  __shared__ int labs[256];
  int t = threadIdx.x;
  int chunk = blockIdx.x;
  labs[t] = y[(chunk * 256 + t) * 3 + 2];
  __syncthreads();
  int lab = labs[t];
  int rank = 0;
  for (int q = 0; q < t; ++q) rank += (labs[q] == lab);
  slots[chunk * 256 + t] = bbase[chunk * NC + lab] + rank;
}

#define ACC_CASE(C) case C: acc[C][0] += xv[u].x; acc[C][1] += xv[u].y; \
                            acc[C][2] += xv[u].z; acc[C][3] += xv[u].w; break;

__global__ void __launch_bounds__(256) k_accum(const float* __restrict__ x,
                                               const int* __restrict__ y,
                                               float* __restrict__ partials) {
  __shared__ int labs[256];
  __shared__ float red[4 * NC * DIM];  // 64 KB
  int t = threadIdx.x;
  int n0 = blockIdx.x * 256;
  labs[t] = y[(n0 + t) * 3 + 2];
  __syncthreads();
  int g = t >> 6, m = t & 63;

  float acc[NC][4];
#pragma unroll
  for (int c = 0; c < NC; ++c)
#pragma unroll
    for (int j = 0; j < 4; ++j) acc[c][j] = 0.f;

  for (int i0 = 0; i0 < 64; i0 += 8) {
    float4 xv[8];
#pragma unroll
    for (int u = 0; u < 8; ++u)
      xv[u] = *(const float4*)(x + (size_t)(n0 + g * 64 + i0 + u) * DIM + m * 4);
#pragma unroll
    for (int u = 0; u < 8; ++u) {
      int lab = __builtin_amdgcn_readfirstlane(labs[g * 64 + i0 + u]);
      switch (lab) {
        ACC_CASE(0) ACC_CASE(1) ACC_CASE(2) ACC_CASE(3)
        ACC_CASE(4) ACC_CASE(5) ACC_CASE(6) ACC_CASE(7)
        ACC_CASE(8) ACC_CASE(9) ACC_CASE(10) ACC_CASE(11)
        ACC_CASE(12) ACC_CASE(13) ACC_CASE(14) ACC_CASE(15)
      }
    }
  }

#pragma unroll
  for (int c = 0; c < NC; ++c)
#pragma unroll
    for (int j = 0; j < 4; ++j)
      red[g * (NC * DIM) + c * DIM + m * 4 + j] = acc[c][j];
  __syncthreads();
  for (int u = t; u < NC * DIM; u += 256) {
    float s = red[u] + red[NC * DIM + u] + red[2 * NC * DIM + u] + red[3 * NC * DIM + u];
    partials[(size_t)blockIdx.x * (NC * DIM) + u] = s;
  }
}

__global__ void __launch_bounds__(256) k_reduce(const float* __restrict__ partials,
                                                float* __restrict__ gsums) {
  int u = blockIdx.x * 256 + threadIdx.x;
  float s = 0.f;
#pragma unroll 8
  for (int b = 0; b < 256; ++b) s += partials[(size_t)b * (NC * DIM) + u];
  gsums[u] = s;
}

__global__ void __launch_bounds__(256) k_centers(const float* __restrict__ gsums,
                                                 const int* __restrict__ gcounts,
                                                 float* __restrict__ centers,
                                                 float* __restrict__ csq) {
  __shared__ float red[DIM];
  int d = threadIdx.x;
  float v[NC];
#pragma unroll
  for (int c = 0; c < NC; ++c) {
    v[c] = gsums[c * DIM + d] / (float)gcounts[c] + EPSV;
    centers[c * DIM + d] = v[c];
  }
#pragma unroll 1
  for (int c = 0; c < NC; ++c) {
    red[d] = v[c] * v[c];
    __syncthreads();
    for (int st = 128; st > 0; st >>= 1) {
      if (d < st) red[d] += red[d + st];
      __syncthreads();
    }
    if (d == 0) csq[c] = red[0];
    __syncthreads();
  }
}

#define ST_CASE(S) case S: _Pragma("unroll") for (int i = 0; i < 4; ++i) { \
    float d2a = csql[2*S]   - 2.f * acc[i][2*S]   + xsq[i]; \
    float d2b = csql[2*S+1] - 2.f * acc[i][2*S+1] + xsq[i]; \
    int sl = slotL[bl + i]; \
    Dmat[(size_t)(2*S)   * NPTS + sl] = sqrtf(fmaxf(d2a, 0.f)); \
    Dmat[(size_t)(2*S+1) * NPTS + sl] = sqrtf(fmaxf(d2b, 0.f)); } break;

// P=4 register blocking: each LDS center read feeds 4 points' FMAs.
// Wave = 32 points (8 pg x 4); lane s=lane&7 owns dims [32s,32s+32).
__global__ void __launch_bounds__(256, 2) k_dist(const float* __restrict__ x,
                                                 const float* __restrict__ centers,
                                                 const float* __restrict__ csq,
                                                 const int* __restrict__ slots,
                                                 float* __restrict__ Dmat) {
  __shared__ float4 cc[NC * 64];  // XOR-swizzled (verified conflict-free)
  __shared__ float csql[NC];
  __shared__ int slotL[128];
  int t = threadIdx.x;
  const float4* cptr = (const float4*)centers;
  for (int u = t; u < NC * 64; u += 256) {
    int q = u & 63;
    int qs = (q & 0x38) | ((q & 7) ^ ((q >> 3) & 7));
    cc[(u & ~63) | qs] = cptr[u];
  }
  if (t < NC) csql[t] = csq[t];
  int pbase = blockIdx.x * 128;
  if (t < 128) slotL[t] = slots[pbase + t];
  __syncthreads();

  int wave = t >> 6, lane = t & 63;
  int s = lane & 7, pg = lane >> 3;
  int bl = wave * 32 + pg * 4;  // local point base (4 points)

  float4 xv[4][8];
#pragma unroll
  for (int i = 0; i < 4; ++i)
#pragma unroll
    for (int j = 0; j < 8; ++j)
      xv[i][j] = *(const float4*)(x + (size_t)(pbase + bl + i) * DIM + s * 32 + j * 4);

  float xsq[4];
#pragma unroll
  for (int i = 0; i < 4; ++i) {
    float q = 0.f;
#pragma unroll
    for (int j = 0; j < 8; ++j)
      q += xv[i][j].x * xv[i][j].x + xv[i][j].y * xv[i][j].y +
           xv[i][j].z * xv[i][j].z + xv[i][j].w * xv[i][j].w;
    xsq[i] = q;
  }

  float acc[4][NC];
#pragma unroll
  for (int i = 0; i < 4; ++i)
#pragma unroll
    for (int c = 0; c < NC; ++c) acc[i][c] = 0.f;

#pragma unroll
  for (int c = 0; c < NC; ++c)
#pragma unroll
    for (int j = 0; j < 8; ++j) {
      float4 cv = cc[c * 64 + s * 8 + (j ^ s)];
#pragma unroll
      for (int i = 0; i < 4; ++i)
        acc[i][c] += xv[i][j].x * cv.x + xv[i][j].y * cv.y +
                     xv[i][j].z * cv.z + xv[i][j].w * cv.w;
    }

  // reduce over the 8 s-lanes (xor1/xor2 lower to DPP, xor4 to swizzle)
#pragma unroll
  for (int i = 0; i < 4; ++i) {
    xsq[i] += __shfl_xor(xsq[i], 1);
    xsq[i] += __shfl_xor(xsq[i], 2);
    xsq[i] += __shfl_xor(xsq[i], 4);
#pragma unroll
    for (int c = 0; c < NC; ++c) {
      acc[i][c] += __shfl_xor(acc[i][c], 1);
      acc[i][c] += __shfl_xor(acc[i][c], 2);
      acc[i][c] += __shfl_xor(acc[i][c], 4);
    }
  }

  // lane s stores classes {2s, 2s+1} for its 4 points (static reg indices)
  switch (s) {
    ST_CASE(0) ST_CASE(1) ST_CASE(2) ST_CASE(3)
    ST_CASE(4) ST_CASE(5) ST_CASE(6) ST_CASE(7)
  }
}

// Radix-select (exact K-th order statistic), then two-pass mean/var.
__global__ void __launch_bounds__(512) k_select(const float* __restrict__ Dmat,
                                                const int* __restrict__ gcounts,
                                                const int* __restrict__ offsets,
                                                float* __restrict__ pos_stat,
                                                float* __restrict__ neg_stat) {
  __shared__ unsigned int keys[VMAX];
  __shared__ int hist[2048];
  __shared__ int sc[512];
  __shared__ float fred[512];
  __shared__ int bsel[2];
  int tid = threadIdx.x;
  int b = blockIdx.x;
  int ci = b >> 4, cl = b & 15;
  bool largest = (ci == cl);
  int cnt = gcounts[cl];
  if (cnt > VMAX) cnt = VMAX;
  int off = offsets[cl];
  const float* src = Dmat + (size_t)ci * NPTS + off;
  unsigned int inv = largest ? 0xFFFFFFFFu : 0u;
  for (int t = tid; t < cnt; t += 512) keys[t] = __float_as_uint(src[t]) ^ inv;
  __syncthreads();

  int target = KSEL;
  unsigned int pfx = 0;

  for (int u = tid; u < 2048; u += 512) hist[u] = 0;
  __syncthreads();
  for (int t = tid; t < cnt; t += 512) atomicAdd(&hist[keys[t] >> 21], 1);
  __syncthreads();
  {
    int segsum = 0;
#pragma unroll
    for (int j = 0; j < 4; ++j) segsum += hist[tid * 4 + j];
    sc[tid] = segsum; __syncthreads();
    for (int ofs = 1; ofs < 512; ofs <<= 1) {
      int v = (tid >= ofs) ? sc[tid - ofs] : 0; __syncthreads();
      sc[tid] += v; __syncthreads();
    }
    int incl = sc[tid], excl = incl - segsum;
    if (excl < target && target <= incl) {
      int run = excl;
      for (int j = 0; j < 4; ++j) {
        int h = hist[tid * 4 + j];
        if (run < target && target <= run + h) { bsel[0] = tid * 4 + j; bsel[1] = target - run; }
        run += h;
      }
    }
    __syncthreads();
    pfx = ((unsigned int)bsel[0]) << 21; target = bsel[1];
  }
  __syncthreads();

  for (int u = tid; u < 2048; u += 512) hist[u] = 0;
  __syncthreads();
  for (int t = tid; t < cnt; t += 512) {
    unsigned int k = keys[t];
    if ((k >> 21) == (pfx >> 21)) atomicAdd(&hist[(k >> 10) & 0x7FF], 1);
  }
  __syncthreads();
  {
    int segsum = 0;
#pragma unroll
    for (int j = 0; j < 4; ++j) segsum += hist[tid * 4 + j];
    sc[tid] = segsum; __syncthreads();
    for (int ofs = 1; ofs < 512; ofs <<= 1) {
      int v = (tid >= ofs) ? sc[tid - ofs] : 0; __syncthreads();
      sc[tid] += v; __syncthreads();
    }
    int incl = sc[tid], excl = incl - segsum;
    if (excl < target && target <= incl) {
      int run = excl;
      for (int j = 0; j < 4; ++j) {
        int h = hist[tid * 4 + j];
        if (run < target && target <= run + h) { bsel[0] = tid * 4 + j; bsel[1] = target - run; }
        run += h;
      }
    }
    __syncthreads();
    pfx |= ((unsigned int)bsel[0]) << 10; target = bsel[1];
  }
  __syncthreads();

  for (int u = tid; u < 1024; u += 512) hist[u] = 0;
  __syncthreads();
  for (int t = tid; t < cnt; t += 512) {
    unsigned int k = keys[t];
    if ((k >> 10) == (pfx >> 10)) atomicAdd(&hist[k & 0x3FF], 1);
  }
  __syncthreads();
  {
    int segsum = hist[tid * 2] + hist[tid * 2 + 1];
    sc[tid] = segsum; __syncthreads();
    for (int ofs = 1; ofs < 512; ofs <<= 1) {
      int v = (tid >= ofs) ? sc[tid - ofs] : 0; __syncthreads();
      sc[tid] += v; __syncthreads();
    }
    int incl = sc[tid], excl = incl - segsum;
    if (excl < target && target <= incl) {
      int run = excl;
      for (int j = 0; j < 2; ++j) {
        int h = hist[tid * 2 + j];
        if (run < target && target <= run + h) { bsel[0] = tid * 2 + j; }
        run += h;
      }
    }
    __syncthreads();
  }
  unsigned int T = pfx | (unsigned int)bsel[0];
  float fT = __uint_as_float(T ^ inv);
  __syncthreads();

  int nl = 0; float sl = 0.f;
  for (int t = tid; t < cnt; t += 512) {
    unsigned int k = keys[t];
    if (k < T) { nl++; sl += __uint_as_float(k ^ inv); }
  }
  sc[tid] = nl; fred[tid] = sl; __syncthreads();
  for (int st = 256; st > 0; st >>= 1) {
    if (tid < st) { sc[tid] += sc[tid + st]; fred[tid] += fred[tid + st]; }
    __syncthreads();
  }
  int n_less = sc[0];
  float mean = (fred[0] + (float)(KSEL - n_less) * fT) / (float)KSEL;
  __syncthreads();

  float sv = 0.f;
  for (int t = tid; t < cnt; t += 512) {
    unsigned int k = keys[t];
    if (k < T) { float d = __uint_as_float(k ^ inv) - mean; sv += d * d; }
  }
  fred[tid] = sv; __syncthreads();
  for (int st = 256; st > 0; st >>= 1) {
    if (tid < st) fred[tid] += fred[tid + st];
    __syncthreads();
  }
  if (tid == 0) {
    float dT = fT - mean;
    float var = (fred[0] + (float)(KSEL - n_less) * dT * dT) / (float)(KSEL - 1);
    if (largest) pos_stat[ci] = mean + 1.96f * sqrtf(var);
    else neg_stat[ci * 16 + cl] = mean - 1.96f * sqrtf(var);
  }
}

__global__ void __launch_bounds__(256) k_loss(const float* __restrict__ pos_stat,
                                              const float* __restrict__ neg_stat,
                                              float* __restrict__ out) {
  __shared__ float red[256];
  int t = threadIdx.x;
  int i = t >> 4, c = t & 15;
  float v = 0.f;
  if (i != c) v = fmaxf(1.0f + pos_stat[i] - neg_stat[t], 0.f);
  red[t] = v; __syncthreads();
  for (int st = 128; st > 0; st >>= 1) { if (t < st) red[t] += red[t + st]; __syncthreads(); }
  if (t == 0) out[0] = red[0];
}

extern "C" void kernel_launch(void* const* d_in, const int* in_sizes, int n_in,
                              void* d_out, int out_size, void* d_ws, size_t ws_size,
                              hipStream_t stream) {
  const float* x = (const float*)d_in[0];
  const int* y = (const int*)d_in[1];
  float* out = (float*)d_out;
  char* ws = (char*)d_ws;

  float* sums = (float*)(ws + 0);
  int* counts = (int*)(ws + 16384);
  int* offsets = (int*)(ws + 16512);
  float* csq = (float*)(ws + 16576);
  float* pos_stat = (float*)(ws + 16640);
  float* neg_stat = (float*)(ws + 16704);
  float* centers = (float*)(ws + 17728);
  int* bhist = (int*)(ws + 34112);
  float* Dmat = (float*)(ws + 65536);
  float* partials = (float*)(ws + 65536);      // consumed before k_dist
  int* slots = (int*)(ws + 4259840);

  k_hist<<<256, 256, 0, stream>>>(y, bhist);
  k_scan<<<1, 256, 0, stream>>>(bhist, counts, offsets);
  k_slot<<<256, 256, 0, stream>>>(y, bhist, slots);
  k_accum<<<256, 256, 0, stream>>>(x, y, partials);
  k_reduce<<<16, 256, 0, stream>>>(partials, sums);
  k_centers<<<1, 256, 0, stream>>>(sums, counts, centers, csq);
  k_dist<<<512, 256, 0, stream>>>(x, centers, csq, slots, Dmat);
  k_select<<<256, 512, 0, stream>>>(Dmat, counts, offsets, pos_stat, neg_stat);
  k_loss<<<1, 256, 0, stream>>>(pos_stat, neg_stat, out);
}

// Round 15
// 110.274 us; speedup vs baseline: 1.0540x; 1.0540x over previous
//
#include <hip/hip_runtime.h>
#include <cfloat>
#include <cstdint>

#define NPTS 65536
#define DIM 256
#define NC 16
#define KSEL 2048
#define VMAX 4608
#define EPSV 1e-6f

// ws layout (bytes):
//     0 : float sums[16*256]   (16384)
// 16384 : int counts[16]       (64)
// 16512 : int offsets[16]      (64)
// 16576 : float csq[16]        (64)
// 16640 : float pos_stat[16]   (64)
// 16704 : float neg_stat[256]  (1024)
// 17728 : float centers[4096]  (16384)
// 34112 : int bhist[256*16]    (16384)
// 65536 : float Dmat[16*65536] (4 MB) -- also start of partials[1024][4096] (16 MB) pre-k_dist
// 16842752 : int slots[65536]  (256 KB)

__global__ void __launch_bounds__(256) k_hist(const int* __restrict__ y,
                                              int* __restrict__ bhist) {
  __shared__ int h[NC];
  int t = threadIdx.x;
  if (t < NC) h[t] = 0;
  __syncthreads();
  int p = blockIdx.x * 256 + t;
  atomicAdd(&h[y[p * 3 + 2]], 1);
  __syncthreads();
  if (t < NC) bhist[blockIdx.x * NC + t] = h[t];
}

// Scan bhist per class across 256 chunks; emits counts/offsets; zeroes gsums.
__global__ void __launch_bounds__(256) k_scan(int* __restrict__ bhist,
                                              int* __restrict__ counts,
                                              int* __restrict__ offsets,
                                              float* __restrict__ gsums) {
  __shared__ int lh[256 * NC];
  __shared__ int segbase[16][NC];
  __shared__ int totl[NC], offl[NC];
  int t = threadIdx.x;
  for (int u = t; u < NC * DIM; u += 256) gsums[u] = 0.f;
  for (int u = t; u < 256 * NC; u += 256) lh[u] = bhist[u];
  __syncthreads();
  int c = t & 15, g = t >> 4;
  int part = 0;
#pragma unroll
  for (int b = 0; b < 16; ++b) part += lh[(g * 16 + b) * NC + c];
  segbase[g][c] = part;
  __syncthreads();
  if (t < NC) {
    int tot = 0;
#pragma unroll
    for (int g2 = 0; g2 < 16; ++g2) tot += segbase[g2][t];
    totl[t] = tot;
    counts[t] = tot;
  }
  __syncthreads();
  if (t == 0) {
    int run = 0;
    for (int c2 = 0; c2 < NC; ++c2) { offl[c2] = run; offsets[c2] = run; run += totl[c2]; }
  }
  __syncthreads();
  if (t < NC) {
    int run = offl[t];
#pragma unroll
    for (int g2 = 0; g2 < 16; ++g2) { int tmp = segbase[g2][t]; segbase[g2][t] = run; run += tmp; }
  }
  __syncthreads();
  int run = segbase[g][c];
#pragma unroll
  for (int b = 0; b < 16; ++b) {
    int idx = (g * 16 + b) * NC + c;
    int tmp = lh[idx]; lh[idx] = run; run += tmp;
  }
  __syncthreads();
  for (int u = t; u < 256 * NC; u += 256) bhist[u] = lh[u];
}

// slot[p] = scanned chunk base + stable in-chunk rank.
__global__ void __launch_bounds__(256) k_slot(const int* __restrict__ y,
                                              const int* __restrict__ bbase,
                                              int* __restrict__ slots) {
  __shared__ int labs[256];
  int t = threadIdx.x;
  int chunk = blockIdx.x;
  labs[t] = y[(chunk * 256 + t) * 3 + 2];
  __syncthreads();
  int lab = labs[t];
  int rank = 0;
  for (int q = 0; q < t; ++q) rank += (labs[q] == lab);
  slots[chunk * 256 + t] = bbase[chunk * NC + lab] + rank;
}

#define ACC_CASE(C) case C: acc[C][0] += xv[u].x; acc[C][1] += xv[u].y; \
                            acc[C][2] += xv[u].z; acc[C][3] += xv[u].w; break;

// 1024 blocks x 64 rows. Wave w owns rows [16w,16w+16) (disjoint ROWS);
// all 64 lanes cover the full row (lane m -> float4 at 4m). Per-wave VGPR
// acc; one end-of-kernel LDS combine -> 16KB block partial. 2 blocks/CU.
__global__ void __launch_bounds__(256) k_accum(const float* __restrict__ x,
                                               const int* __restrict__ y,
                                               float* __restrict__ partials) {
  __shared__ int labs[64];
  __shared__ float red[4 * NC * DIM];  // 64 KB
  int t = threadIdx.x;
  int n0 = blockIdx.x * 64;
  if (t < 64) labs[t] = y[(n0 + t) * 3 + 2];
  __syncthreads();
  int w = t >> 6, m = t & 63;

  float acc[NC][4];
#pragma unroll
  for (int c = 0; c < NC; ++c)
#pragma unroll
    for (int j = 0; j < 4; ++j) acc[c][j] = 0.f;

  for (int r0 = 0; r0 < 16; r0 += 4) {
    float4 xv[4];
#pragma unroll
    for (int u = 0; u < 4; ++u)
      xv[u] = *(const float4*)(x + (size_t)(n0 + 16 * w + r0 + u) * DIM + 4 * m);
#pragma unroll
    for (int u = 0; u < 4; ++u) {
      int lab = __builtin_amdgcn_readfirstlane(labs[16 * w + r0 + u]);
      switch (lab) {
        ACC_CASE(0) ACC_CASE(1) ACC_CASE(2) ACC_CASE(3)
        ACC_CASE(4) ACC_CASE(5) ACC_CASE(6) ACC_CASE(7)
        ACC_CASE(8) ACC_CASE(9) ACC_CASE(10) ACC_CASE(11)
        ACC_CASE(12) ACC_CASE(13) ACC_CASE(14) ACC_CASE(15)
      }
    }
  }

#pragma unroll
  for (int c = 0; c < NC; ++c)
#pragma unroll
    for (int j = 0; j < 4; ++j)
      red[w * (NC * DIM) + c * DIM + 4 * m + j] = acc[c][j];
  __syncthreads();
  for (int u = t; u < NC * DIM; u += 256) {
    float s = red[u] + red[NC * DIM + u] + red[2 * NC * DIM + u] + red[3 * NC * DIM + u];
    partials[(size_t)blockIdx.x * (NC * DIM) + u] = s;
  }
}

// 8 slices x 128 chunks each over 1024 partials; combined via atomicAdd.
__global__ void __launch_bounds__(256) k_reduce(const float* __restrict__ partials,
                                                float* __restrict__ gsums) {
  int tg = blockIdx.x * 256 + threadIdx.x;  // 128 blocks -> 32768 threads
  int u = tg & 4095;
  int s = tg >> 12;  // slice 0..7
  float acc = 0.f;
#pragma unroll 8
  for (int b = s * 128; b < s * 128 + 128; ++b)
    acc += partials[(size_t)b * (NC * DIM) + u];
  atomicAdd(&gsums[u], acc);
}

__global__ void __launch_bounds__(256) k_centers(const float* __restrict__ gsums,
                                                 const int* __restrict__ gcounts,
                                                 float* __restrict__ centers,
                                                 float* __restrict__ csq) {
  __shared__ float red[DIM];
  int d = threadIdx.x;
  float v[NC];
#pragma unroll
  for (int c = 0; c < NC; ++c) {
    v[c] = gsums[c * DIM + d] / (float)gcounts[c] + EPSV;
    centers[c * DIM + d] = v[c];
  }
#pragma unroll 1
  for (int c = 0; c < NC; ++c) {
    red[d] = v[c] * v[c];
    __syncthreads();
    for (int st = 128; st > 0; st >>= 1) {
      if (d < st) red[d] += red[d + st];
      __syncthreads();
    }
    if (d == 0) csq[c] = red[0];
    __syncthreads();
  }
}

#define ST_CASE(S) case S: _Pragma("unroll") for (int i = 0; i < 4; ++i) { \
    float d2a = csql[2*S]   - 2.f * acc[i][2*S]   + xsq[i]; \
    float d2b = csql[2*S+1] - 2.f * acc[i][2*S+1] + xsq[i]; \
    int sl = slotL[bl + i]; \
    Dmat[(size_t)(2*S)   * NPTS + sl] = sqrtf(fmaxf(d2a, 0.f)); \
    Dmat[(size_t)(2*S+1) * NPTS + sl] = sqrtf(fmaxf(d2b, 0.f)); } break;

__global__ void __launch_bounds__(256, 2) k_dist(const float* __restrict__ x,
                                                 const float* __restrict__ centers,
                                                 const float* __restrict__ csq,
                                                 const int* __restrict__ slots,
                                                 float* __restrict__ Dmat) {
  __shared__ float4 cc[NC * 64];
  __shared__ float csql[NC];
  __shared__ int slotL[128];
  int t = threadIdx.x;
  const float4* cptr = (const float4*)centers;
  for (int u = t; u < NC * 64; u += 256) {
    int q = u & 63;
    int qs = (q & 0x38) | ((q & 7) ^ ((q >> 3) & 7));
    cc[(u & ~63) | qs] = cptr[u];
  }
  if (t < NC) csql[t] = csq[t];
  int pbase = blockIdx.x * 128;
  if (t < 128) slotL[t] = slots[pbase + t];
  __syncthreads();

  int wave = t >> 6, lane = t & 63;
  int s = lane & 7, pg = lane >> 3;
  int bl = wave * 32 + pg * 4;

  float4 xv[4][8];
#pragma unroll
  for (int i = 0; i < 4; ++i)
#pragma unroll
    for (int j = 0; j < 8; ++j)
      xv[i][j] = *(const float4*)(x + (size_t)(pbase + bl + i) * DIM + s * 32 + j * 4);

  float xsq[4];
#pragma unroll
  for (int i = 0; i < 4; ++i) {
    float q = 0.f;
#pragma unroll
    for (int j = 0; j < 8; ++j)
      q += xv[i][j].x * xv[i][j].x + xv[i][j].y * xv[i][j].y +
           xv[i][j].z * xv[i][j].z + xv[i][j].w * xv[i][j].w;
    xsq[i] = q;
  }

  float acc[4][NC];
#pragma unroll
  for (int i = 0; i < 4; ++i)
#pragma unroll
    for (int c = 0; c < NC; ++c) acc[i][c] = 0.f;

#pragma unroll
  for (int c = 0; c < NC; ++c)
#pragma unroll
    for (int j = 0; j < 8; ++j) {
      float4 cv = cc[c * 64 + s * 8 + (j ^ s)];
#pragma unroll
      for (int i = 0; i < 4; ++i)
        acc[i][c] += xv[i][j].x * cv.x + xv[i][j].y * cv.y +
                     xv[i][j].z * cv.z + xv[i][j].w * cv.w;
    }

#pragma unroll
  for (int i = 0; i < 4; ++i) {
    xsq[i] += __shfl_xor(xsq[i], 1);
    xsq[i] += __shfl_xor(xsq[i], 2);
    xsq[i] += __shfl_xor(xsq[i], 4);
#pragma unroll
    for (int c = 0; c < NC; ++c) {
      acc[i][c] += __shfl_xor(acc[i][c], 1);
      acc[i][c] += __shfl_xor(acc[i][c], 2);
      acc[i][c] += __shfl_xor(acc[i][c], 4);
    }
  }

  switch (s) {
    ST_CASE(0) ST_CASE(1) ST_CASE(2) ST_CASE(3)
    ST_CASE(4) ST_CASE(5) ST_CASE(6) ST_CASE(7)
  }
}

// Radix-select (exact K-th order statistic), then two-pass mean/var.
__global__ void __launch_bounds__(512) k_select(const float* __restrict__ Dmat,
                                                const int* __restrict__ gcounts,
                                                const int* __restrict__ offsets,
                                                float* __restrict__ pos_stat,
                                                float* __restrict__ neg_stat) {
  __shared__ unsigned int keys[VMAX];
  __shared__ int hist[2048];
  __shared__ int sc[512];
  __shared__ float fred[512];
  __shared__ int bsel[2];
  int tid = threadIdx.x;
  int b = blockIdx.x;
  int ci = b >> 4, cl = b & 15;
  bool largest = (ci == cl);
  int cnt = gcounts[cl];
  if (cnt > VMAX) cnt = VMAX;
  int off = offsets[cl];
  const float* src = Dmat + (size_t)ci * NPTS + off;
  unsigned int inv = largest ? 0xFFFFFFFFu : 0u;
  for (int t = tid; t < cnt; t += 512) keys[t] = __float_as_uint(src[t]) ^ inv;
  __syncthreads();

  int target = KSEL;
  unsigned int pfx = 0;

  for (int u = tid; u < 2048; u += 512) hist[u] = 0;
  __syncthreads();
  for (int t = tid; t < cnt; t += 512) atomicAdd(&hist[keys[t] >> 21], 1);
  __syncthreads();
  {
    int segsum = 0;
#pragma unroll
    for (int j = 0; j < 4; ++j) segsum += hist[tid * 4 + j];
    sc[tid] = segsum; __syncthreads();
    for (int ofs = 1; ofs < 512; ofs <<= 1) {
      int v = (tid >= ofs) ? sc[tid - ofs] : 0; __syncthreads();
      sc[tid] += v; __syncthreads();
    }
    int incl = sc[tid], excl = incl - segsum;
    if (excl < target && target <= incl) {
      int run = excl;
      for (int j = 0; j < 4; ++j) {
        int h = hist[tid * 4 + j];
        if (run < target && target <= run + h) { bsel[0] = tid * 4 + j; bsel[1] = target - run; }
        run += h;
      }
    }
    __syncthreads();
    pfx = ((unsigned int)bsel[0]) << 21; target = bsel[1];
  }
  __syncthreads();

  for (int u = tid; u < 2048; u += 512) hist[u] = 0;
  __syncthreads();
  for (int t = tid; t < cnt; t += 512) {
    unsigned int k = keys[t];
    if ((k >> 21) == (pfx >> 21)) atomicAdd(&hist[(k >> 10) & 0x7FF], 1);
  }
  __syncthreads();
  {
    int segsum = 0;
#pragma unroll
    for (int j = 0; j < 4; ++j) segsum += hist[tid * 4 + j];
    sc[tid] = segsum; __syncthreads();
    for (int ofs = 1; ofs < 512; ofs <<= 1) {
      int v = (tid >= ofs) ? sc[tid - ofs] : 0; __syncthreads();
      sc[tid] += v; __syncthreads();
    }
    int incl = sc[tid], excl = incl - segsum;
    if (excl < target && target <= incl) {
      int run = excl;
      for (int j = 0; j < 4; ++j) {
        int h = hist[tid * 4 + j];
        if (run < target && target <= run + h) { bsel[0] = tid * 4 + j; bsel[1] = target - run; }
        run += h;
      }
    }
    __syncthreads();
    pfx |= ((unsigned int)bsel[0]) << 10; target = bsel[1];
  }
  __syncthreads();

  for (int u = tid; u < 1024; u += 512) hist[u] = 0;
  __syncthreads();
  for (int t = tid; t < cnt; t += 512) {
    unsigned int k = keys[t];
    if ((k >> 10) == (pfx >> 10)) atomicAdd(&hist[k & 0x3FF], 1);
  }
  __syncthreads();
  {
    int segsum = hist[tid * 2] + hist[tid * 2 + 1];
    sc[tid] = segsum; __syncthreads();
    for (int ofs = 1; ofs < 512; ofs <<= 1) {
      int v = (tid >= ofs) ? sc[tid - ofs] : 0; __syncthreads();
      sc[tid] += v; __syncthreads();
    }
    int incl = sc[tid], excl = incl - segsum;
    if (excl < target && target <= incl) {
      int run = excl;
      for (int j = 0; j < 2; ++j) {
        int h = hist[tid * 2 + j];
        if (run < target && target <= run + h) { bsel[0] = tid * 2 + j; }
        run += h;
      }
    }
    __syncthreads();
  }
  unsigned int T = pfx | (unsigned int)bsel[0];
  float fT = __uint_as_float(T ^ inv);
  __syncthreads();

  int nl = 0; float sl = 0.f;
  for (int t = tid; t < cnt; t += 512) {
    unsigned int k = keys[t];
    if (k < T) { nl++; sl += __uint_as_float(k ^ inv); }
  }
  sc[tid] = nl; fred[tid] = sl; __syncthreads();
  for (int st = 256; st > 0; st >>= 1) {
    if (tid < st) { sc[tid] += sc[tid + st]; fred[tid] += fred[tid + st]; }
    __syncthreads();
  }
  int n_less = sc[0];
  float mean = (fred[0] + (float)(KSEL - n_less) * fT) / (float)KSEL;
  __syncthreads();

  float sv = 0.f;
  for (int t = tid; t < cnt; t += 512) {
    unsigned int k = keys[t];
    if (k < T) { float d = __uint_as_float(k ^ inv) - mean; sv += d * d; }
  }
  fred[tid] = sv; __syncthreads();
  for (int st = 256; st > 0; st >>= 1) {
    if (tid < st) fred[tid] += fred[tid + st];
    __syncthreads();
  }
  if (tid == 0) {
    float dT = fT - mean;
    float var = (fred[0] + (float)(KSEL - n_less) * dT * dT) / (float)(KSEL - 1);
    if (largest) pos_stat[ci] = mean + 1.96f * sqrtf(var);
    else neg_stat[ci * 16 + cl] = mean - 1.96f * sqrtf(var);
  }
}

__global__ void __launch_bounds__(256) k_loss(const float* __restrict__ pos_stat,
                                              const float* __restrict__ neg_stat,
                                              float* __restrict__ out) {
  __shared__ float red[256];
  int t = threadIdx.x;
  int i = t >> 4, c = t & 15;
  float v = 0.f;
  if (i != c) v = fmaxf(1.0f + pos_stat[i] - neg_stat[t], 0.f);
  red[t] = v; __syncthreads();
  for (int st = 128; st > 0; st >>= 1) { if (t < st) red[t] += red[t + st]; __syncthreads(); }
  if (t == 0) out[0] = red[0];
}

extern "C" void kernel_launch(void* const* d_in, const int* in_sizes, int n_in,
                              void* d_out, int out_size, void* d_ws, size_t ws_size,
                              hipStream_t stream) {
  const float* x = (const float*)d_in[0];
  const int* y = (const int*)d_in[1];
  float* out = (float*)d_out;
  char* ws = (char*)d_ws;

  float* sums = (float*)(ws + 0);
  int* counts = (int*)(ws + 16384);
  int* offsets = (int*)(ws + 16512);
  float* csq = (float*)(ws + 16576);
  float* pos_stat = (float*)(ws + 16640);
  float* neg_stat = (float*)(ws + 16704);
  float* centers = (float*)(ws + 17728);
  int* bhist = (int*)(ws + 34112);
  float* Dmat = (float*)(ws + 65536);
  float* partials = (float*)(ws + 65536);   // [1024][4096] = 16 MB, consumed pre-k_dist
  int* slots = (int*)(ws + 16842752);

  k_hist<<<256, 256, 0, stream>>>(y, bhist);
  k_scan<<<1, 256, 0, stream>>>(bhist, counts, offsets, sums);
  k_slot<<<256, 256, 0, stream>>>(y, bhist, slots);
  k_accum<<<1024, 256, 0, stream>>>(x, y, partials);
  k_reduce<<<128, 256, 0, stream>>>(partials, sums);
  k_centers<<<1, 256, 0, stream>>>(sums, counts, centers, csq);
  k_dist<<<512, 256, 0, stream>>>(x, centers, csq, slots, Dmat);
  k_select<<<256, 512, 0, stream>>>(Dmat, counts, offsets, pos_stat, neg_stat);
  k_loss<<<1, 256, 0, stream>>>(pos_stat, neg_stat, out);
}

// Round 16
// 102.470 us; speedup vs baseline: 1.1343x; 1.0762x over previous
//
#include <hip/hip_runtime.h>
#include <cfloat>
#include <cstdint>

#define NPTS 65536
#define DIM 256
#define NC 16
#define KSEL 2048
#define VMAX 4608
#define EPSV 1e-6f

// ws layout (bytes):
//     0 : float sums[16*256]   (16384)
// 16384 : int counts[16]       (64)
// 16512 : int offsets[16]      (64)
// 16576 : float csq[16]        (64)
// 16640 : float pos_stat[16]   (64)
// 16704 : float neg_stat[256]  (1024)
// 17728 : float centers[4096]  (16384)
// 34112 : int bhist[256*16]    (16384)
// 65536 : float Dmat[16*65536] (4 MB) -- also start of partials[1024][4096] (16 MB) pre-k_dist
// 16842752 : int slots[65536]  (256 KB)

__global__ void __launch_bounds__(256) k_hist(const int* __restrict__ y,
                                              int* __restrict__ bhist) {
  __shared__ int h[NC];
  int t = threadIdx.x;
  if (t < NC) h[t] = 0;
  __syncthreads();
  int p = blockIdx.x * 256 + t;
  atomicAdd(&h[y[p * 3 + 2]], 1);
  __syncthreads();
  if (t < NC) bhist[blockIdx.x * NC + t] = h[t];
}

// Scan bhist per class across 256 chunks; emits counts/offsets; zeroes gsums.
__global__ void __launch_bounds__(256) k_scan(int* __restrict__ bhist,
                                              int* __restrict__ counts,
                                              int* __restrict__ offsets,
                                              float* __restrict__ gsums) {
  __shared__ int lh[256 * NC];
  __shared__ int segbase[16][NC];
  __shared__ int totl[NC], offl[NC];
  int t = threadIdx.x;
  for (int u = t; u < NC * DIM; u += 256) gsums[u] = 0.f;
  for (int u = t; u < 256 * NC; u += 256) lh[u] = bhist[u];
  __syncthreads();
  int c = t & 15, g = t >> 4;
  int part = 0;
#pragma unroll
  for (int b = 0; b < 16; ++b) part += lh[(g * 16 + b) * NC + c];
  segbase[g][c] = part;
  __syncthreads();
  if (t < NC) {
    int tot = 0;
#pragma unroll
    for (int g2 = 0; g2 < 16; ++g2) tot += segbase[g2][t];
    totl[t] = tot;
    counts[t] = tot;
  }
  __syncthreads();
  if (t == 0) {
    int run = 0;
    for (int c2 = 0; c2 < NC; ++c2) { offl[c2] = run; offsets[c2] = run; run += totl[c2]; }
  }
  __syncthreads();
  if (t < NC) {
    int run = offl[t];
#pragma unroll
    for (int g2 = 0; g2 < 16; ++g2) { int tmp = segbase[g2][t]; segbase[g2][t] = run; run += tmp; }
  }
  __syncthreads();
  int run = segbase[g][c];
#pragma unroll
  for (int b = 0; b < 16; ++b) {
    int idx = (g * 16 + b) * NC + c;
    int tmp = lh[idx]; lh[idx] = run; run += tmp;
  }
  __syncthreads();
  for (int u = t; u < 256 * NC; u += 256) bhist[u] = lh[u];
}

// slot[p] = scanned chunk base + stable in-chunk rank.
__global__ void __launch_bounds__(256) k_slot(const int* __restrict__ y,
                                              const int* __restrict__ bbase,
                                              int* __restrict__ slots) {
  __shared__ int labs[256];
  int t = threadIdx.x;
  int chunk = blockIdx.x;
  labs[t] = y[(chunk * 256 + t) * 3 + 2];
  __syncthreads();
  int lab = labs[t];
  int rank = 0;
  for (int q = 0; q < t; ++q) rank += (labs[q] == lab);
  slots[chunk * 256 + t] = bbase[chunk * NC + lab] + rank;
}

#define ACC_CASE(C) case C: acc[C][0] += xv[u].x; acc[C][1] += xv[u].y; \
                            acc[C][2] += xv[u].z; acc[C][3] += xv[u].w; break;

// 1024 blocks x 64 rows. Wave w owns rows [16w,16w+16) (disjoint ROWS);
// all 64 lanes cover the full row (lane m -> float4 at 4m). Per-wave VGPR
// acc; one end-of-kernel LDS combine -> 16KB block partial. 2 blocks/CU.
__global__ void __launch_bounds__(256) k_accum(const float* __restrict__ x,
                                               const int* __restrict__ y,
                                               float* __restrict__ partials) {
  __shared__ int labs[64];
  __shared__ float red[4 * NC * DIM];  // 64 KB
  int t = threadIdx.x;
  int n0 = blockIdx.x * 64;
  if (t < 64) labs[t] = y[(n0 + t) * 3 + 2];
  __syncthreads();
  int w = t >> 6, m = t & 63;

  float acc[NC][4];
#pragma unroll
  for (int c = 0; c < NC; ++c)
#pragma unroll
    for (int j = 0; j < 4; ++j) acc[c][j] = 0.f;

  for (int r0 = 0; r0 < 16; r0 += 4) {
    float4 xv[4];
#pragma unroll
    for (int u = 0; u < 4; ++u)
      xv[u] = *(const float4*)(x + (size_t)(n0 + 16 * w + r0 + u) * DIM + 4 * m);
#pragma unroll
    for (int u = 0; u < 4; ++u) {
      int lab = __builtin_amdgcn_readfirstlane(labs[16 * w + r0 + u]);
      switch (lab) {
        ACC_CASE(0) ACC_CASE(1) ACC_CASE(2) ACC_CASE(3)
        ACC_CASE(4) ACC_CASE(5) ACC_CASE(6) ACC_CASE(7)
        ACC_CASE(8) ACC_CASE(9) ACC_CASE(10) ACC_CASE(11)
        ACC_CASE(12) ACC_CASE(13) ACC_CASE(14) ACC_CASE(15)
      }
    }
  }

#pragma unroll
  for (int c = 0; c < NC; ++c)
#pragma unroll
    for (int j = 0; j < 4; ++j)
      red[w * (NC * DIM) + c * DIM + 4 * m + j] = acc[c][j];
  __syncthreads();
  for (int u = t; u < NC * DIM; u += 256) {
    float s = red[u] + red[NC * DIM + u] + red[2 * NC * DIM + u] + red[3 * NC * DIM + u];
    partials[(size_t)blockIdx.x * (NC * DIM) + u] = s;
  }
}

// 8 slices x 128 chunks each over 1024 partials; combined via atomicAdd.
__global__ void __launch_bounds__(256) k_reduce(const float* __restrict__ partials,
                                                float* __restrict__ gsums) {
  int tg = blockIdx.x * 256 + threadIdx.x;  // 128 blocks -> 32768 threads
  int u = tg & 4095;
  int s = tg >> 12;  // slice 0..7
  float acc = 0.f;
#pragma unroll 8
  for (int b = s * 128; b < s * 128 + 128; ++b)
    acc += partials[(size_t)b * (NC * DIM) + u];
  atomicAdd(&gsums[u], acc);
}

__global__ void __launch_bounds__(256) k_centers(const float* __restrict__ gsums,
                                                 const int* __restrict__ gcounts,
                                                 float* __restrict__ centers,
                                                 float* __restrict__ csq) {
  __shared__ float red[DIM];
  int d = threadIdx.x;
  float v[NC];
#pragma unroll
  for (int c = 0; c < NC; ++c) {
    v[c] = gsums[c * DIM + d] / (float)gcounts[c] + EPSV;
    centers[c * DIM + d] = v[c];
  }
#pragma unroll 1
  for (int c = 0; c < NC; ++c) {
    red[d] = v[c] * v[c];
    __syncthreads();
    for (int st = 128; st > 0; st >>= 1) {
      if (d < st) red[d] += red[d + st];
      __syncthreads();
    }
    if (d == 0) csq[c] = red[0];
    __syncthreads();
  }
}

#define ST_CASE(S) case S: _Pragma("unroll") for (int i = 0; i < 2; ++i) { \
    float d2a = csql[2*S]   - 2.f * acc[i][2*S]   + xsq[i]; \
    float d2b = csql[2*S+1] - 2.f * acc[i][2*S+1] + xsq[i]; \
    int sl = slotL[bl + i]; \
    Dmat[(size_t)(2*S)   * NPTS + sl] = sqrtf(fmaxf(d2a, 0.f)); \
    Dmat[(size_t)(2*S+1) * NPTS + sl] = sqrtf(fmaxf(d2b, 0.f)); } break;

// P=2, L=8: wave = 16 points, block = 64 points, grid 1024 -> 4 blocks/CU
// -> 16 waves/CU (2x the P=4 version). xv[2][8]~64 VGPR keeps 4 waves/SIMD.
__global__ void __launch_bounds__(256, 4) k_dist(const float* __restrict__ x,
                                                 const float* __restrict__ centers,
                                                 const float* __restrict__ csq,
                                                 const int* __restrict__ slots,
                                                 float* __restrict__ Dmat) {
  __shared__ float4 cc[NC * 64];
  __shared__ float csql[NC];
  __shared__ int slotL[64];
  int t = threadIdx.x;
  const float4* cptr = (const float4*)centers;
  for (int u = t; u < NC * 64; u += 256) {
    int q = u & 63;
    int qs = (q & 0x38) | ((q & 7) ^ ((q >> 3) & 7));
    cc[(u & ~63) | qs] = cptr[u];
  }
  if (t < NC) csql[t] = csq[t];
  int pbase = blockIdx.x * 64;
  if (t < 64) slotL[t] = slots[pbase + t];
  __syncthreads();

  int wave = t >> 6, lane = t & 63;
  int s = lane & 7, pg = lane >> 3;
  int bl = wave * 16 + pg * 2;  // local point base (2 points)

  float4 xv[2][8];
#pragma unroll
  for (int i = 0; i < 2; ++i)
#pragma unroll
    for (int j = 0; j < 8; ++j)
      xv[i][j] = *(const float4*)(x + (size_t)(pbase + bl + i) * DIM + s * 32 + j * 4);

  float xsq[2];
#pragma unroll
  for (int i = 0; i < 2; ++i) {
    float q = 0.f;
#pragma unroll
    for (int j = 0; j < 8; ++j)
      q += xv[i][j].x * xv[i][j].x + xv[i][j].y * xv[i][j].y +
           xv[i][j].z * xv[i][j].z + xv[i][j].w * xv[i][j].w;
    xsq[i] = q;
  }

  float acc[2][NC];
#pragma unroll
  for (int i = 0; i < 2; ++i)
#pragma unroll
    for (int c = 0; c < NC; ++c) acc[i][c] = 0.f;

#pragma unroll
  for (int c = 0; c < NC; ++c)
#pragma unroll
    for (int j = 0; j < 8; ++j) {
      float4 cv = cc[c * 64 + s * 8 + (j ^ s)];
#pragma unroll
      for (int i = 0; i < 2; ++i)
        acc[i][c] += xv[i][j].x * cv.x + xv[i][j].y * cv.y +
                     xv[i][j].z * cv.z + xv[i][j].w * cv.w;
    }

#pragma unroll
  for (int i = 0; i < 2; ++i) {
    xsq[i] += __shfl_xor(xsq[i], 1);
    xsq[i] += __shfl_xor(xsq[i], 2);
    xsq[i] += __shfl_xor(xsq[i], 4);
#pragma unroll
    for (int c = 0; c < NC; ++c) {
      acc[i][c] += __shfl_xor(acc[i][c], 1);
      acc[i][c] += __shfl_xor(acc[i][c], 2);
      acc[i][c] += __shfl_xor(acc[i][c], 4);
    }
  }

  switch (s) {
    ST_CASE(0) ST_CASE(1) ST_CASE(2) ST_CASE(3)
    ST_CASE(4) ST_CASE(5) ST_CASE(6) ST_CASE(7)
  }
}

// Radix-select (exact K-th order statistic), then two-pass mean/var.
__global__ void __launch_bounds__(512) k_select(const float* __restrict__ Dmat,
                                                const int* __restrict__ gcounts,
                                                const int* __restrict__ offsets,
                                                float* __restrict__ pos_stat,
                                                float* __restrict__ neg_stat) {
  __shared__ unsigned int keys[VMAX];
  __shared__ int hist[2048];
  __shared__ int sc[512];
  __shared__ float fred[512];
  __shared__ int bsel[2];
  int tid = threadIdx.x;
  int b = blockIdx.x;
  int ci = b >> 4, cl = b & 15;
  bool largest = (ci == cl);
  int cnt = gcounts[cl];
  if (cnt > VMAX) cnt = VMAX;
  int off = offsets[cl];
  const float* src = Dmat + (size_t)ci * NPTS + off;
  unsigned int inv = largest ? 0xFFFFFFFFu : 0u;
  for (int t = tid; t < cnt; t += 512) keys[t] = __float_as_uint(src[t]) ^ inv;
  __syncthreads();

  int target = KSEL;
  unsigned int pfx = 0;

  for (int u = tid; u < 2048; u += 512) hist[u] = 0;
  __syncthreads();
  for (int t = tid; t < cnt; t += 512) atomicAdd(&hist[keys[t] >> 21], 1);
  __syncthreads();
  {
    int segsum = 0;
#pragma unroll
    for (int j = 0; j < 4; ++j) segsum += hist[tid * 4 + j];
    sc[tid] = segsum; __syncthreads();
    for (int ofs = 1; ofs < 512; ofs <<= 1) {
      int v = (tid >= ofs) ? sc[tid - ofs] : 0; __syncthreads();
      sc[tid] += v; __syncthreads();
    }
    int incl = sc[tid], excl = incl - segsum;
    if (excl < target && target <= incl) {
      int run = excl;
      for (int j = 0; j < 4; ++j) {
        int h = hist[tid * 4 + j];
        if (run < target && target <= run + h) { bsel[0] = tid * 4 + j; bsel[1] = target - run; }
        run += h;
      }
    }
    __syncthreads();
    pfx = ((unsigned int)bsel[0]) << 21; target = bsel[1];
  }
  __syncthreads();

  for (int u = tid; u < 2048; u += 512) hist[u] = 0;
  __syncthreads();
  for (int t = tid; t < cnt; t += 512) {
    unsigned int k = keys[t];
    if ((k >> 21) == (pfx >> 21)) atomicAdd(&hist[(k >> 10) & 0x7FF], 1);
  }
  __syncthreads();
  {
    int segsum = 0;
#pragma unroll
    for (int j = 0; j < 4; ++j) segsum += hist[tid * 4 + j];
    sc[tid] = segsum; __syncthreads();
    for (int ofs = 1; ofs < 512; ofs <<= 1) {
      int v = (tid >= ofs) ? sc[tid - ofs] : 0; __syncthreads();
      sc[tid] += v; __syncthreads();
    }
    int incl = sc[tid], excl = incl - segsum;
    if (excl < target && target <= incl) {
      int run = excl;
      for (int j = 0; j < 4; ++j) {
        int h = hist[tid * 4 + j];
        if (run < target && target <= run + h) { bsel[0] = tid * 4 + j; bsel[1] = target - run; }
        run += h;
      }
    }
    __syncthreads();
    pfx |= ((unsigned int)bsel[0]) << 10; target = bsel[1];
  }
  __syncthreads();

  for (int u = tid; u < 1024; u += 512) hist[u] = 0;
  __syncthreads();
  for (int t = tid; t < cnt; t += 512) {
    unsigned int k = keys[t];
    if ((k >> 10) == (pfx >> 10)) atomicAdd(&hist[k & 0x3FF], 1);
  }
  __syncthreads();
  {
    int segsum = hist[tid * 2] + hist[tid * 2 + 1];
    sc[tid] = segsum; __syncthreads();
    for (int ofs = 1; ofs < 512; ofs <<= 1) {
      int v = (tid >= ofs) ? sc[tid - ofs] : 0; __syncthreads();
      sc[tid] += v; __syncthreads();
    }
    int incl = sc[tid], excl = incl - segsum;
    if (excl < target && target <= incl) {
      int run = excl;
      for (int j = 0; j < 2; ++j) {
        int h = hist[tid * 2 + j];
        if (run < target && target <= run + h) { bsel[0] = tid * 2 + j; }
        run += h;
      }
    }
    __syncthreads();
  }
  unsigned int T = pfx | (unsigned int)bsel[0];
  float fT = __uint_as_float(T ^ inv);
  __syncthreads();

  int nl = 0; float sl = 0.f;
  for (int t = tid; t < cnt; t += 512) {
    unsigned int k = keys[t];
    if (k < T) { nl++; sl += __uint_as_float(k ^ inv); }
  }
  sc[tid] = nl; fred[tid] = sl; __syncthreads();
  for (int st = 256; st > 0; st >>= 1) {
    if (tid < st) { sc[tid] += sc[tid + st]; fred[tid] += fred[tid + st]; }
    __syncthreads();
  }
  int n_less = sc[0];
  float mean = (fred[0] + (float)(KSEL - n_less) * fT) / (float)KSEL;
  __syncthreads();

  float sv = 0.f;
  for (int t = tid; t < cnt; t += 512) {
    unsigned int k = keys[t];
    if (k < T) { float d = __uint_as_float(k ^ inv) - mean; sv += d * d; }
  }
  fred[tid] = sv; __syncthreads();
  for (int st = 256; st > 0; st >>= 1) {
    if (tid < st) fred[tid] += fred[tid + st];
    __syncthreads();
  }
  if (tid == 0) {
    float dT = fT - mean;
    float var = (fred[0] + (float)(KSEL - n_less) * dT * dT) / (float)(KSEL - 1);
    if (largest) pos_stat[ci] = mean + 1.96f * sqrtf(var);
    else neg_stat[ci * 16 + cl] = mean - 1.96f * sqrtf(var);
  }
}

__global__ void __launch_bounds__(256) k_loss(const float* __restrict__ pos_stat,
                                              const float* __restrict__ neg_stat,
                                              float* __restrict__ out) {
  __shared__ float red[256];
  int t = threadIdx.x;
  int i = t >> 4, c = t & 15;
  float v = 0.f;
  if (i != c) v = fmaxf(1.0f + pos_stat[i] - neg_stat[t], 0.f);
  red[t] = v; __syncthreads();
  for (int st = 128; st > 0; st >>= 1) { if (t < st) red[t] += red[t + st]; __syncthreads(); }
  if (t == 0) out[0] = red[0];
}

extern "C" void kernel_launch(void* const* d_in, const int* in_sizes, int n_in,
                              void* d_out, int out_size, void* d_ws, size_t ws_size,
                              hipStream_t stream) {
  const float* x = (const float*)d_in[0];
  const int* y = (const int*)d_in[1];
  float* out = (float*)d_out;
  char* ws = (char*)d_ws;

  float* sums = (float*)(ws + 0);
  int* counts = (int*)(ws + 16384);
  int* offsets = (int*)(ws + 16512);
  float* csq = (float*)(ws + 16576);
  float* pos_stat = (float*)(ws + 16640);
  float* neg_stat = (float*)(ws + 16704);
  float* centers = (float*)(ws + 17728);
  int* bhist = (int*)(ws + 34112);
  float* Dmat = (float*)(ws + 65536);
  float* partials = (float*)(ws + 65536);   // [1024][4096] = 16 MB, consumed pre-k_dist
  int* slots = (int*)(ws + 16842752);

  k_hist<<<256, 256, 0, stream>>>(y, bhist);
  k_scan<<<1, 256, 0, stream>>>(bhist, counts, offsets, sums);
  k_slot<<<256, 256, 0, stream>>>(y, bhist, slots);
  k_accum<<<1024, 256, 0, stream>>>(x, y, partials);
  k_reduce<<<128, 256, 0, stream>>>(partials, sums);
  k_centers<<<1, 256, 0, stream>>>(sums, counts, centers, csq);
  k_dist<<<1024, 256, 0, stream>>>(x, centers, csq, slots, Dmat);
  k_select<<<256, 512, 0, stream>>>(Dmat, counts, offsets, pos_stat, neg_stat);
  k_loss<<<1, 256, 0, stream>>>(pos_stat, neg_stat, out);
}